// Round 1
// 434.686 us; speedup vs baseline: 1.2108x; 1.2108x over previous
//
#include <hip/hip_runtime.h>
#include <type_traits>
#include <utility>

// ---------------------------------------------------------------------------
// HyenaFilter: y[b,c,l] = sum_{j<=l} k[c,j] x[b,c,l-j] + bias[c] x[b,c,l]
// Direct causal conv as bf16 MFMA 32x32x16, one 1024-thread block per channel.
// R4: LDS-bandwidth fix. Inner loop was 21.3 FLOP per LDS byte vs ~36 needed
// to feed the matrix pipe (per-iter 3072 B for 2 MFMA). Now 2 A-tiles
// (Delta, Delta+256) x 5 B-tiles (Toeplitz share B(a,D)=B(a+1,D+256)) feed
// 8 MFMAs into 4 acc tiles: 7168 B / 8 MFMA = 36.6 FLOP/B. Each wave owns
// 1024 l-positions; triangle balanced via 2-way K-split per group
// (per-SIMD iter sums exactly 288), partials reduced through LDS (sKR
// reused as f32 scratch). LPAD 496->1008 absorbs the wider tile overshoot.
// Filter kernel: grid (256,3) for 12 waves/CU + float4 LDS reads (was
// 1 wave/SIMD with 6144 scalar ds_read broadcasts per wave).
// ---------------------------------------------------------------------------

typedef __attribute__((ext_vector_type(4))) short  short4v;
typedef __attribute__((ext_vector_type(8))) short  short8v;
typedef __attribute__((ext_vector_type(8))) __bf16 bf16x8;
typedef __attribute__((ext_vector_type(16))) float f32x16;

// --- MFMA builtin operand-type hedge (short8 vs v8bf16) --------------------
template <typename V, typename = void> struct MfmaTakes : std::false_type {};
template <typename V>
struct MfmaTakes<V, std::void_t<decltype(__builtin_amdgcn_mfma_f32_32x32x16_bf16(
    std::declval<V>(), std::declval<V>(), std::declval<f32x16>(), 0, 0, 0))>>
    : std::true_type {};

template <bool UseBf16> struct MfmaImpl;
template <> struct MfmaImpl<true> {
  template <typename V>
  static __device__ inline f32x16 run(V a, V b, f32x16 c) {
    return __builtin_amdgcn_mfma_f32_32x32x16_bf16(
        __builtin_bit_cast(bf16x8, a), __builtin_bit_cast(bf16x8, b), c, 0, 0, 0);
  }
};
template <> struct MfmaImpl<false> {
  template <typename V>
  static __device__ inline f32x16 run(V a, V b, f32x16 c) {
    return __builtin_amdgcn_mfma_f32_32x32x16_bf16(a, b, c, 0, 0, 0);
  }
};

__device__ inline f32x16 mfma_bf16(short8v a, short8v b, f32x16 c) {
  return MfmaImpl<MfmaTakes<bf16x8>::value>::run(a, b, c);
}

__device__ inline short8v pack8(short4v lo, short4v hi) {
  short8v v;
  v[0] = lo[0]; v[1] = lo[1]; v[2] = lo[2]; v[3] = lo[3];
  v[4] = hi[0]; v[5] = hi[1]; v[6] = hi[2]; v[7] = hi[3];
  return v;
}

// float -> bf16 bits, round-to-nearest-even (finite values only)
__device__ inline short f2bf(float f) {
  unsigned int u = __builtin_bit_cast(unsigned int, f);
  u += 0x7FFFu + ((u >> 16) & 1u);
  return (short)(u >> 16);
}
__device__ inline float bf2f(short s) {
  unsigned int u = ((unsigned int)(unsigned short)s) << 16;
  return __builtin_bit_cast(float, u);
}

// ---------------------------------------------------------------------------
// Kernel 1: filter generation.  gk[c*8192 + l] = bf16(k[c,l])
// grid (256, 3): blockIdx.x = 32-l slice, blockIdx.y = 256-channel slice.
// MLP stages computed redundantly per c-slice (cheap); Wout stage does
// exactly one channel per thread with float4 LDS broadcasts.
// ---------------------------------------------------------------------------
__global__ __launch_bounds__(256) void hyena_filter(
    const float* __restrict__ z, const float* __restrict__ deltas,
    const float* __restrict__ W0, const float* __restrict__ b0,
    const float* __restrict__ W1, const float* __restrict__ b1,
    const float* __restrict__ W2, const float* __restrict__ b2,
    const float* __restrict__ freq, const float* __restrict__ Wout,
    short* __restrict__ gk) {
  __shared__ float zt[32][33];
  __shared__ __align__(16) float hA[32][64];
  __shared__ __align__(16) float hB[32][64];
  const int tid = threadIdx.x;
  const int l0 = blockIdx.x << 5;

  for (int i = tid; i < 32 * 33; i += 256) {
    int l = i / 33, e = i - l * 33;
    zt[l][e] = z[(l0 + l) * 33 + e];
  }
  __syncthreads();
  for (int i = tid; i < 2048; i += 256) {
    int l = i >> 6, o = i & 63;
    float s = b0[o];
    for (int e = 0; e < 33; ++e) s += zt[l][e] * W0[e * 64 + o];
    hA[l][o] = sinf(freq[o] * s);
  }
  __syncthreads();
  for (int i = tid; i < 2048; i += 256) {
    int l = i >> 6, o = i & 63;
    float s = b1[o];
#pragma unroll
    for (int e = 0; e < 64; e += 4) {
      const float4 h4 = *reinterpret_cast<const float4*>(&hA[l][e]);
      s += h4.x * W1[e * 64 + o] + h4.y * W1[(e + 1) * 64 + o] +
           h4.z * W1[(e + 2) * 64 + o] + h4.w * W1[(e + 3) * 64 + o];
    }
    hB[l][o] = sinf(freq[o] * s);
  }
  __syncthreads();
  for (int i = tid; i < 2048; i += 256) {
    int l = i >> 6, o = i & 63;
    float s = b2[o];
#pragma unroll
    for (int e = 0; e < 64; e += 4) {
      const float4 h4 = *reinterpret_cast<const float4*>(&hB[l][e]);
      s += h4.x * W2[e * 64 + o] + h4.y * W2[(e + 1) * 64 + o] +
           h4.z * W2[(e + 2) * 64 + o] + h4.w * W2[(e + 3) * 64 + o];
    }
    hA[l][o] = sinf(freq[o] * s);
  }
  __syncthreads();
  {
    const int c0 = (blockIdx.y << 8) + tid;  // one channel per thread
    float a32[32];
#pragma unroll
    for (int l = 0; l < 32; ++l) a32[l] = 0.f;
    for (int o = 0; o < 64; o += 4) {
      const float w0 = Wout[(o + 0) * 768 + c0];
      const float w1 = Wout[(o + 1) * 768 + c0];
      const float w2 = Wout[(o + 2) * 768 + c0];
      const float w3 = Wout[(o + 3) * 768 + c0];
#pragma unroll
      for (int l = 0; l < 32; ++l) {
        const float4 h4 = *reinterpret_cast<const float4*>(&hA[l][o]);
        a32[l] += h4.x * w0 + h4.y * w1 + h4.z * w2 + h4.w * w3;
      }
    }
    const float del = fabsf(deltas[c0]);
    unsigned int* gku = reinterpret_cast<unsigned int*>(gk + (c0 << 13) + l0);
#pragma unroll
    for (int l = 0; l < 32; l += 2) {
      float t0 = (float)(l0 + l) * (1.f / 8191.f);
      float t1 = (float)(l0 + l + 1) * (1.f / 8191.f);
      unsigned short v0 = (unsigned short)f2bf(a32[l] * expf(-t0 * del));
      unsigned short v1 = (unsigned short)f2bf(a32[l + 1] * expf(-t1 * del));
      gku[l >> 1] = (unsigned int)v0 | ((unsigned int)v1 << 16);
    }
  }
}

// ---------------------------------------------------------------------------
// Kernel 2: causal conv via MFMA. 1024 threads (16 waves) per channel.
//
// LDS: sKR[rho][u] = KR[u+rho], KR[t] = k[8207-t] for t in [16,8207] else 0.
//      sXB[b][1008+s] = bf16(x[b,c,s]); [0,1008) zero (absorbs tile-a reads
//      up to 992 left of the data under the Na=4 tiling), [9200,9224) pad.
//      Row = 9224 shorts = 4612 dw == 4 (mod 32): same measured
//      conflict-free layout class as R3.
// Wave wid -> (G, h): G = group of 1024 l (acc tiles a=0..3 at +256a),
//      h = K-half. Per-SIMD iteration sums exactly 288.
// Per iter at Delta0 (step 16 within 512-blocks, +512 across):
//   A0 = A(Delta0), A1 = A(Delta0+256)   (2x b64 each, sKR 4-replica)
//   B(w) at xa+256w, w=-1..3             (5x b128)
//   acc[a] += A0*B(a) + A1*B(a-1)        (8 MFMA; B shared via Toeplitz)
// After K loop: h=1 waves dump acc into sKR-as-f32-scratch (2 tiles/phase,
// 8 slots x 8 KB), h=0 waves add and write the epilogue (float4 stores).
// ---------------------------------------------------------------------------

#define ACC_ST(ACC, OFF)                                              \
  do {                                                                \
    _Pragma("unroll") for (int q = 0; q < 4; ++q) {                   \
      float4 v;                                                       \
      v.x = ACC[4 * q + 0]; v.y = ACC[4 * q + 1];                     \
      v.z = ACC[4 * q + 2]; v.w = ACC[4 * q + 3];                     \
      *reinterpret_cast<float4*>(sp + (OFF) + (q << 8)) = v;          \
    }                                                                 \
  } while (0)

#define ACC_LD(ACC, OFF)                                              \
  do {                                                                \
    _Pragma("unroll") for (int q = 0; q < 4; ++q) {                   \
      const float4 v =                                                \
          *reinterpret_cast<const float4*>(sp + (OFF) + (q << 8));    \
      ACC[4 * q + 0] += v.x; ACC[4 * q + 1] += v.y;                   \
      ACC[4 * q + 2] += v.z; ACC[4 * q + 3] += v.w;                   \
    }                                                                 \
  } while (0)

#define EPI(ACC, A)                                                   \
  do {                                                                \
    const int lb = lwb + ((A) << 8);                                  \
    _Pragma("unroll") for (int q = 0; q < 4; ++q) {                   \
      const int l0q = lb + (q << 3);                                  \
      const short4v xs =                                              \
          *reinterpret_cast<const short4v*>(&sXB[bcol][1008 + l0q]);  \
      float4 o4;                                                      \
      o4.x = ACC[4 * q + 0] + bc * bf2f(xs[0]);                       \
      o4.y = ACC[4 * q + 1] + bc * bf2f(xs[1]);                       \
      o4.z = ACC[4 * q + 2] + bc * bf2f(xs[2]);                       \
      o4.w = ACC[4 * q + 3] + bc * bf2f(xs[3]);                       \
      *reinterpret_cast<float4*>(out + obase + l0q) = o4;             \
    }                                                                 \
  } while (0)

__global__ __launch_bounds__(1024, 4) void hyena_conv(
    const float* __restrict__ x, const float* __restrict__ bias,
    const short* __restrict__ gk, float* __restrict__ out) {
  constexpr int LPAD = 1008;
  constexpr int XROW = 9224;                       // 1008 + 8192 + 24 pad
  __shared__ __align__(16) short sKR[4][8240];     // 65920 B (+ f32 scratch)
  __shared__ __align__(16) short sXB[4][XROW];     // 73792 B ; total 139712 B
  const int c = blockIdx.x;
  const int tid = threadIdx.x;

  // stage x -> bf16 LDS rows (1008 leading zeros, 24 tail pad)
  for (int b = 0; b < 4; ++b) {
    const float* xr = x + ((b * 768 + c) << 13);
    for (int p = tid; p < XROW; p += 1024) {
      short v = 0;
      if (p >= LPAD && p < LPAD + 8192) v = f2bf(xr[p - LPAD]);
      sXB[b][p] = v;
    }
  }
  // stage reversed filter, 4 shifted replicas
  {
    const short* gkr = gk + (c << 13);
    for (int r = 0; r < 4; ++r)
      for (int u = tid; u < 8240; u += 1024) {
        int t = u + r;
        short v = 0;
        if (t >= 16 && t <= 8207) v = gkr[8207 - t];
        sKR[r][u] = v;
      }
  }
  __syncthreads();

  const int lane = tid & 63;
  const int wid  = tid >> 6;                       // 0..15
  const int i31  = lane & 31;
  const int half = lane >> 5;
  const int base = half << 3;
  const int tcol = i31 >> 2;
  const int bcol = i31 & 3;
  const float bc = bias[c];

  // wave -> (G, h): per-SIMD (wid&3) iteration sums all equal 288.
  // j=wid>>1: G = {0,1,7,6,2,3,5,4}[j]; h = wid&1 (K half).
  const int j  = wid >> 1;
  const int t2 = ((j >> 2) << 1) | (j & 1);
  const int G  = (j & 2) ? (7 - t2) : t2;
  const int h  = wid & 1;
  const int NB = G + 1;                            // 512-blocks per K half
  const int lbase = G << 10;

  const int af0 = 8207 - i31 + base;
  const int rho = af0 & 3;
  const int u00 = af0 & ~3;
  const int pb  = LPAD + lbase + (tcol << 5) + base;
  const int d0  = (h * NB) << 9;                   // 512 * starting block

  const short* ka = &sKR[rho][0] + (u00 + 16 - d0);
  const short* xa = &sXB[bcol][0] + (pb + 16 - d0);

  f32x16 acc0, acc1, acc2, acc3;
#pragma unroll
  for (int r = 0; r < 16; ++r) {
    acc0[r] = 0.f; acc1[r] = 0.f; acc2[r] = 0.f; acc3[r] = 0.f;
  }

  for (int blk = 0; blk < NB; ++blk) {
#pragma unroll 2
    for (int t = 0; t < 16; ++t) {
      const short4v a0lo = *reinterpret_cast<const short4v*>(ka);
      const short4v a0hi = *reinterpret_cast<const short4v*>(ka + 4);
      const short4v a1lo = *reinterpret_cast<const short4v*>(ka - 256);
      const short4v a1hi = *reinterpret_cast<const short4v*>(ka - 252);
      const short8v A0 = pack8(a0lo, a0hi);
      const short8v A1 = pack8(a1lo, a1hi);
      const short8v Bm1 = *reinterpret_cast<const short8v*>(xa - 256);
      const short8v B0  = *reinterpret_cast<const short8v*>(xa);
      acc0 = mfma_bf16(A1, Bm1, acc0);
      acc0 = mfma_bf16(A0, B0, acc0);
      const short8v B1 = *reinterpret_cast<const short8v*>(xa + 256);
      acc1 = mfma_bf16(A1, B0, acc1);
      acc1 = mfma_bf16(A0, B1, acc1);
      const short8v B2 = *reinterpret_cast<const short8v*>(xa + 512);
      acc2 = mfma_bf16(A1, B1, acc2);
      acc2 = mfma_bf16(A0, B2, acc2);
      const short8v B3 = *reinterpret_cast<const short8v*>(xa + 768);
      acc3 = mfma_bf16(A1, B2, acc3);
      acc3 = mfma_bf16(A0, B3, acc3);
      ka -= 16; xa -= 16;
    }
    ka -= 256; xa -= 256;                          // skip s=1-covered half
  }

  // 2-way K-split reduction: sKR reused as f32 scratch (8 slots x 2048 f32)
  __syncthreads();
  float* scr = reinterpret_cast<float*>(&sKR[0][0]);
  float* sp = scr + ((wid >> 1) << 11) + (lane << 2);
  if (h) { ACC_ST(acc0, 0); ACC_ST(acc1, 1024); }
  __syncthreads();
  if (!h) { ACC_LD(acc0, 0); ACC_LD(acc1, 1024); }
  __syncthreads();
  if (h) { ACC_ST(acc2, 0); ACC_ST(acc3, 1024); }
  __syncthreads();
  if (!h) {
    ACC_LD(acc2, 0); ACC_LD(acc3, 1024);
    // epilogue: y = acc + bias*x  (x read back from LDS as bf16)
    const int obase = ((bcol * 768 + c) << 13);
    const int lwb = lbase + (tcol << 5) + (half << 2);
    EPI(acc0, 0); EPI(acc1, 1); EPI(acc2, 2); EPI(acc3, 3);
  }
}

// ---------------------------------------------------------------------------
extern "C" void kernel_launch(void* const* d_in, const int* in_sizes, int n_in,
                              void* d_out, int out_size, void* d_ws, size_t ws_size,
                              hipStream_t stream) {
  const float* x      = (const float*)d_in[0];
  const float* bias   = (const float*)d_in[1];
  const float* z      = (const float*)d_in[2];
  const float* deltas = (const float*)d_in[3];
  const float* W0     = (const float*)d_in[4];
  const float* b0     = (const float*)d_in[5];
  const float* W1     = (const float*)d_in[6];
  const float* b1     = (const float*)d_in[7];
  const float* W2     = (const float*)d_in[8];
  const float* b2     = (const float*)d_in[9];
  const float* freq   = (const float*)d_in[10];
  const float* Wout   = (const float*)d_in[11];
  float* out = (float*)d_out;
  short* gk = (short*)d_ws;  // 768*8192*2 B = 12.6 MB filter workspace

  hipLaunchKernelGGL(hyena_filter, dim3(256, 3), dim3(256), 0, stream,
                     z, deltas, W0, b0, W1, b1, W2, b2, freq, Wout, gk);
  hipLaunchKernelGGL(hyena_conv, dim3(768), dim3(1024), 0, stream,
                     x, bias, gk, out);
}

// Round 2
// 407.144 us; speedup vs baseline: 1.2927x; 1.0676x over previous
//
#include <hip/hip_runtime.h>
#include <type_traits>
#include <utility>

// ---------------------------------------------------------------------------
// HyenaFilter: y[b,c,l] = sum_{j<=l} k[c,j] x[b,c,l-j] + bias[c] x[b,c,l]
// Direct causal conv as bf16 MFMA 32x32x16, one 1024-thread block per channel.
// R5: wave-balance fix. R4's per-SIMD iteration SUMS were equal (288) but
// individual waves ran 16..128 iters -> long tail with 1 wave/SIMD exposing
// MFMA+DS latency (round 88us vs 40us LDS floor). Now waves/group =
// {1,1,1,2,2,3,3,3} with spans 32..96 iters, SIMD-packed to exactly 288
// each: SIMD0{96,64,64,64} SIMD1{86,85,85,32} SIMD2{80,80,64,64}
// SIMD3{75,75,74,64}. Generalized reduction: 8 storer waves -> 8x8KB
// scratch slots (sKR reuse), 8 owner waves add + epilogue.
// Filter kernel: gk stores were 64x scattered 4B txns per wave-instr
// (channel-per-thread, 16KB stride). Now LDS-transpose + cooperative
// dwordx4 stores (16 full 64B lines per instr), and gk stored REVERSED
// (gkR[c][i] = k[8191-i]) so conv's sKR staging reads forward.
// x staging vectorized: 2x float4 global + ds_write_b128 per chunk.
// ---------------------------------------------------------------------------

typedef __attribute__((ext_vector_type(4))) short  short4v;
typedef __attribute__((ext_vector_type(8))) short  short8v;
typedef __attribute__((ext_vector_type(8))) __bf16 bf16x8;
typedef __attribute__((ext_vector_type(16))) float f32x16;

// --- MFMA builtin operand-type hedge (short8 vs v8bf16) --------------------
template <typename V, typename = void> struct MfmaTakes : std::false_type {};
template <typename V>
struct MfmaTakes<V, std::void_t<decltype(__builtin_amdgcn_mfma_f32_32x32x16_bf16(
    std::declval<V>(), std::declval<V>(), std::declval<f32x16>(), 0, 0, 0))>>
    : std::true_type {};

template <bool UseBf16> struct MfmaImpl;
template <> struct MfmaImpl<true> {
  template <typename V>
  static __device__ inline f32x16 run(V a, V b, f32x16 c) {
    return __builtin_amdgcn_mfma_f32_32x32x16_bf16(
        __builtin_bit_cast(bf16x8, a), __builtin_bit_cast(bf16x8, b), c, 0, 0, 0);
  }
};
template <> struct MfmaImpl<false> {
  template <typename V>
  static __device__ inline f32x16 run(V a, V b, f32x16 c) {
    return __builtin_amdgcn_mfma_f32_32x32x16_bf16(a, b, c, 0, 0, 0);
  }
};

__device__ inline f32x16 mfma_bf16(short8v a, short8v b, f32x16 c) {
  return MfmaImpl<MfmaTakes<bf16x8>::value>::run(a, b, c);
}

__device__ inline short8v pack8(short4v lo, short4v hi) {
  short8v v;
  v[0] = lo[0]; v[1] = lo[1]; v[2] = lo[2]; v[3] = lo[3];
  v[4] = hi[0]; v[5] = hi[1]; v[6] = hi[2]; v[7] = hi[3];
  return v;
}

// float -> bf16 bits, round-to-nearest-even (finite values only)
__device__ inline short f2bf(float f) {
  unsigned int u = __builtin_bit_cast(unsigned int, f);
  u += 0x7FFFu + ((u >> 16) & 1u);
  return (short)(u >> 16);
}
__device__ inline float bf2f(short s) {
  unsigned int u = ((unsigned int)(unsigned short)s) << 16;
  return __builtin_bit_cast(float, u);
}

// --- R5 wave->work mapping tables (see header comment) ---------------------
__device__ const unsigned char cGt[16]  = {2,7,4,6,1,7,4,6,5,7,3,6,3,0,5,5};
__device__ const short         cN0[16]  = {0,0,0,0,0,86,80,75,0,171,64,150,0,0,64,128};
__device__ const short         cN1[16]  = {96,86,80,75,64,171,160,150,64,256,128,224,64,32,128,192};
__device__ const unsigned char cSLOT[16]= {255,255,255,255,255,0,1,2,255,3,4,5,255,255,6,7};
__device__ const unsigned char cRA[16]  = {255,0,1,2,255,255,255,255,6,255,255,255,4,255,255,255};
__device__ const unsigned char cRB[16]  = {255,3,255,5,255,255,255,255,7,255,255,255,255,255,255,255};

// ---------------------------------------------------------------------------
// Kernel 1: filter generation.  gkR[c][i] = bf16(k[c, 8191-i])  (REVERSED)
// grid (256, 3): blockIdx.x = 32-l slice, blockIdx.y = 256-channel slice.
// ---------------------------------------------------------------------------
__global__ __launch_bounds__(256) void hyena_filter(
    const float* __restrict__ z, const float* __restrict__ deltas,
    const float* __restrict__ W0, const float* __restrict__ b0,
    const float* __restrict__ W1, const float* __restrict__ b1,
    const float* __restrict__ W2, const float* __restrict__ b2,
    const float* __restrict__ freq, const float* __restrict__ Wout,
    short* __restrict__ gk) {
  __shared__ float zt[32][33];
  __shared__ __align__(16) float hA[32][64];
  __shared__ __align__(16) float hB[32][64];
  __shared__ __align__(16) unsigned int sT[256][20];  // transpose tile
  const int tid = threadIdx.x;
  const int l0 = blockIdx.x << 5;

  for (int i = tid; i < 32 * 33; i += 256) {
    int l = i / 33, e = i - l * 33;
    zt[l][e] = z[(l0 + l) * 33 + e];
  }
  __syncthreads();
  for (int i = tid; i < 2048; i += 256) {
    int l = i >> 6, o = i & 63;
    float s = b0[o];
    for (int e = 0; e < 33; ++e) s += zt[l][e] * W0[e * 64 + o];
    hA[l][o] = sinf(freq[o] * s);
  }
  __syncthreads();
  for (int i = tid; i < 2048; i += 256) {
    int l = i >> 6, o = i & 63;
    float s = b1[o];
#pragma unroll
    for (int e = 0; e < 64; e += 4) {
      const float4 h4 = *reinterpret_cast<const float4*>(&hA[l][e]);
      s += h4.x * W1[e * 64 + o] + h4.y * W1[(e + 1) * 64 + o] +
           h4.z * W1[(e + 2) * 64 + o] + h4.w * W1[(e + 3) * 64 + o];
    }
    hB[l][o] = sinf(freq[o] * s);
  }
  __syncthreads();
  for (int i = tid; i < 2048; i += 256) {
    int l = i >> 6, o = i & 63;
    float s = b2[o];
#pragma unroll
    for (int e = 0; e < 64; e += 4) {
      const float4 h4 = *reinterpret_cast<const float4*>(&hB[l][e]);
      s += h4.x * W2[e * 64 + o] + h4.y * W2[(e + 1) * 64 + o] +
           h4.z * W2[(e + 2) * 64 + o] + h4.w * W2[(e + 3) * 64 + o];
    }
    hA[l][o] = sinf(freq[o] * s);
  }
  __syncthreads();
  {
    const int c0 = (blockIdx.y << 8) + tid;  // one channel per thread
    float a32[32];
#pragma unroll
    for (int l = 0; l < 32; ++l) a32[l] = 0.f;
    for (int o = 0; o < 64; o += 4) {
      const float w0 = Wout[(o + 0) * 768 + c0];
      const float w1 = Wout[(o + 1) * 768 + c0];
      const float w2 = Wout[(o + 2) * 768 + c0];
      const float w3 = Wout[(o + 3) * 768 + c0];
#pragma unroll
      for (int l = 0; l < 32; ++l) {
        const float4 h4 = *reinterpret_cast<const float4*>(&hA[l][o]);
        a32[l] += h4.x * w0 + h4.y * w1 + h4.z * w2 + h4.w * w3;
      }
    }
    const float del = fabsf(deltas[c0]);
#pragma unroll
    for (int l = 0; l < 32; ++l) {
      const float t = (float)(l0 + l) * (1.f / 8191.f);
      a32[l] *= expf(-t * del);
    }
    // pack reversed pairs: dword d = { lo=k[l0+31-2d], hi=k[l0+30-2d] }
#pragma unroll
    for (int d = 0; d < 16; ++d) {
      const unsigned int lo = (unsigned short)f2bf(a32[31 - 2 * d]);
      const unsigned int hi = (unsigned short)f2bf(a32[30 - 2 * d]);
      sT[tid][d] = lo | (hi << 16);
    }
  }
  __syncthreads();
  {
    // cooperative store: 4 lanes per channel row -> 16 full 64B lines/instr
    const int lane = tid & 63, wid = tid >> 6;
    const int base_dw = 4080 - (blockIdx.x << 4);
    unsigned int* gku = reinterpret_cast<unsigned int*>(gk);
#pragma unroll
    for (int q = 0; q < 4; ++q) {
      const int r = (wid << 6) + (q << 4) + (lane >> 2);
      const int m = (lane & 3) << 2;
      const uint4 v = *reinterpret_cast<const uint4*>(&sT[r][m]);
      const size_t cg = (size_t)((blockIdx.y << 8) + r);
      *reinterpret_cast<uint4*>(gku + cg * 4096 + base_dw + m) = v;
    }
  }
}

// ---------------------------------------------------------------------------
// Kernel 2: causal conv via MFMA. 1024 threads (16 waves) per channel.
//
// LDS: sKR[rho][u] = KR[u+rho], KR[t] = k[8207-t] = gkR[t-16] for t in
//      [16,8207] else 0.  sXB[b][1008+s] = bf16(x[b,c,s]); [0,1008) zero,
//      [9200,9224) pad. Row = 9224 shorts = 4612 dw == 4 (mod 32).
// Wave wid -> (G, [n0,n1)) via tables; iteration n: d = 512*(n>>4)+16*(n&15),
// pointers decrement 16/iter, extra 256 at block end ((n&15)==15).
// Per iter: A0,A1 (2x b64 each) x B(-1..3) (5x b128) -> 8 MFMA, 4 acc tiles:
//   acc[a] += A0*B(a) + A1*B(a-1)   (Toeplitz share)
// Reduction: storer waves (slot 0..7) dump acc pairs into sKR-as-f32 scratch
// (8 x 8KB), owner waves add their group's 0-2 slots and run the epilogue.
// ---------------------------------------------------------------------------

#define ACC_ST(ACC, P, OFF)                                           \
  do {                                                                \
    _Pragma("unroll") for (int q = 0; q < 4; ++q) {                   \
      float4 v;                                                       \
      v.x = ACC[4 * q + 0]; v.y = ACC[4 * q + 1];                     \
      v.z = ACC[4 * q + 2]; v.w = ACC[4 * q + 3];                     \
      *reinterpret_cast<float4*>((P) + (OFF) + (q << 8)) = v;         \
    }                                                                 \
  } while (0)

#define ACC_LD(ACC, P, OFF)                                           \
  do {                                                                \
    _Pragma("unroll") for (int q = 0; q < 4; ++q) {                   \
      const float4 v =                                                \
          *reinterpret_cast<const float4*>((P) + (OFF) + (q << 8));   \
      ACC[4 * q + 0] += v.x; ACC[4 * q + 1] += v.y;                   \
      ACC[4 * q + 2] += v.z; ACC[4 * q + 3] += v.w;                   \
    }                                                                 \
  } while (0)

#define EPI(ACC, A)                                                   \
  do {                                                                \
    const int lb = lwb + ((A) << 8);                                  \
    _Pragma("unroll") for (int q = 0; q < 4; ++q) {                   \
      const int l0q = lb + (q << 3);                                  \
      const short4v xs =                                              \
          *reinterpret_cast<const short4v*>(&sXB[bcol][1008 + l0q]);  \
      float4 o4;                                                      \
      o4.x = ACC[4 * q + 0] + bc * bf2f(xs[0]);                       \
      o4.y = ACC[4 * q + 1] + bc * bf2f(xs[1]);                       \
      o4.z = ACC[4 * q + 2] + bc * bf2f(xs[2]);                       \
      o4.w = ACC[4 * q + 3] + bc * bf2f(xs[3]);                       \
      *reinterpret_cast<float4*>(out + obase + l0q) = o4;             \
    }                                                                 \
  } while (0)

__global__ __launch_bounds__(1024, 4) void hyena_conv(
    const float* __restrict__ x, const float* __restrict__ bias,
    const short* __restrict__ gk, float* __restrict__ out) {
  constexpr int LPAD = 1008;
  constexpr int XROW = 9224;                       // 1008 + 8192 + 24 pad
  __shared__ __align__(16) short sKR[4][8240];     // 65920 B (+ f32 scratch)
  __shared__ __align__(16) short sXB[4][XROW];     // 73792 B ; total 139712 B
  const int c = blockIdx.x;
  const int tid = threadIdx.x;

  // stage x -> bf16 LDS rows, vectorized (2x float4 -> ds_write_b128)
  {
    const short8v z8 = {0, 0, 0, 0, 0, 0, 0, 0};
    for (int b = 0; b < 4; ++b) {
      const float* xr = x + ((b * 768 + c) << 13);
      if (tid < 126)
        *reinterpret_cast<short8v*>(&sXB[b][tid << 3]) = z8;
      if (tid >= 1021)
        *reinterpret_cast<short8v*>(&sXB[b][9200 + ((tid - 1021) << 3)]) = z8;
      const int s0 = tid << 3;
      const float4 f0 = *reinterpret_cast<const float4*>(xr + s0);
      const float4 f1 = *reinterpret_cast<const float4*>(xr + s0 + 4);
      short8v v;
      v[0] = f2bf(f0.x); v[1] = f2bf(f0.y); v[2] = f2bf(f0.z); v[3] = f2bf(f0.w);
      v[4] = f2bf(f1.x); v[5] = f2bf(f1.y); v[6] = f2bf(f1.z); v[7] = f2bf(f1.w);
      *reinterpret_cast<short8v*>(&sXB[b][LPAD + s0]) = v;
    }
  }
  // stage reversed filter, 4 shifted replicas (gk already reversed: forward reads)
  {
    const short* gkr = gk + (c << 13);
    for (int r = 0; r < 4; ++r)
      for (int u = tid; u < 8240; u += 1024) {
        int t = u + r;
        short v = 0;
        if (t >= 16 && t <= 8207) v = gkr[t - 16];
        sKR[r][u] = v;
      }
  }
  __syncthreads();

  const int lane = tid & 63;
  const int wid  = tid >> 6;                       // 0..15
  const int i31  = lane & 31;
  const int half = lane >> 5;
  const int base = half << 3;
  const int tcol = i31 >> 2;
  const int bcol = i31 & 3;
  const float bc = bias[c];

  const int G    = cGt[wid];
  const int n0   = cN0[wid];
  const int n1   = cN1[wid];
  const int slot = cSLOT[wid];
  const int lbase = G << 10;

  const int af0 = 8207 - i31 + base;
  const int rho = af0 & 3;
  const int u00 = af0 & ~3;
  const int pb  = LPAD + lbase + (tcol << 5) + base;
  const int d0  = ((n0 >> 4) << 9) + ((n0 & 15) << 4);

  const short* ka = &sKR[rho][0] + (u00 + 16 - d0);
  const short* xa = &sXB[bcol][0] + (pb + 16 - d0);

  f32x16 acc0, acc1, acc2, acc3;
#pragma unroll
  for (int r = 0; r < 16; ++r) {
    acc0[r] = 0.f; acc1[r] = 0.f; acc2[r] = 0.f; acc3[r] = 0.f;
  }

#pragma unroll 2
  for (int n = n0; n < n1; ++n) {
    const short4v a0lo = *reinterpret_cast<const short4v*>(ka);
    const short4v a0hi = *reinterpret_cast<const short4v*>(ka + 4);
    const short4v a1lo = *reinterpret_cast<const short4v*>(ka - 256);
    const short4v a1hi = *reinterpret_cast<const short4v*>(ka - 252);
    const short8v A0 = pack8(a0lo, a0hi);
    const short8v A1 = pack8(a1lo, a1hi);
    const short8v Bm1 = *reinterpret_cast<const short8v*>(xa - 256);
    const short8v B0  = *reinterpret_cast<const short8v*>(xa);
    acc0 = mfma_bf16(A1, Bm1, acc0);
    acc0 = mfma_bf16(A0, B0, acc0);
    const short8v B1 = *reinterpret_cast<const short8v*>(xa + 256);
    acc1 = mfma_bf16(A1, B0, acc1);
    acc1 = mfma_bf16(A0, B1, acc1);
    const short8v B2 = *reinterpret_cast<const short8v*>(xa + 512);
    acc2 = mfma_bf16(A1, B1, acc2);
    acc2 = mfma_bf16(A0, B2, acc2);
    const short8v B3 = *reinterpret_cast<const short8v*>(xa + 768);
    acc3 = mfma_bf16(A1, B2, acc3);
    acc3 = mfma_bf16(A0, B3, acc3);
    const int dec = 16 + (((n & 15) == 15) << 8);
    ka -= dec; xa -= dec;
  }

  // generalized K-split reduction: sKR reused as f32 scratch (8 x 2048 f32)
  __syncthreads();
  float* scr = reinterpret_cast<float*>(&sKR[0][0]);
  const int isOwner = (slot == 255);
  float* sp = scr + (isOwner ? 0 : slot * 2048) + (lane << 2);
  const int ra = cRA[wid], rb = cRB[wid];
  if (!isOwner) { ACC_ST(acc0, sp, 0); ACC_ST(acc1, sp, 1024); }
  __syncthreads();
  if (isOwner) {
    if (ra != 255) {
      float* lp = scr + ra * 2048 + (lane << 2);
      ACC_LD(acc0, lp, 0); ACC_LD(acc1, lp, 1024);
    }
    if (rb != 255) {
      float* lp = scr + rb * 2048 + (lane << 2);
      ACC_LD(acc0, lp, 0); ACC_LD(acc1, lp, 1024);
    }
  }
  __syncthreads();
  if (!isOwner) { ACC_ST(acc2, sp, 0); ACC_ST(acc3, sp, 1024); }
  __syncthreads();
  if (isOwner) {
    if (ra != 255) {
      float* lp = scr + ra * 2048 + (lane << 2);
      ACC_LD(acc2, lp, 0); ACC_LD(acc3, lp, 1024);
    }
    if (rb != 255) {
      float* lp = scr + rb * 2048 + (lane << 2);
      ACC_LD(acc2, lp, 0); ACC_LD(acc3, lp, 1024);
    }
    // epilogue: y = acc + bias*x  (x read back from LDS as bf16)
    const int obase = ((bcol * 768 + c) << 13);
    const int lwb = lbase + (tcol << 5) + (half << 2);
    EPI(acc0, 0); EPI(acc1, 1); EPI(acc2, 2); EPI(acc3, 3);
  }
}

// ---------------------------------------------------------------------------
extern "C" void kernel_launch(void* const* d_in, const int* in_sizes, int n_in,
                              void* d_out, int out_size, void* d_ws, size_t ws_size,
                              hipStream_t stream) {
  const float* x      = (const float*)d_in[0];
  const float* bias   = (const float*)d_in[1];
  const float* z      = (const float*)d_in[2];
  const float* deltas = (const float*)d_in[3];
  const float* W0     = (const float*)d_in[4];
  const float* b0     = (const float*)d_in[5];
  const float* W1     = (const float*)d_in[6];
  const float* b1     = (const float*)d_in[7];
  const float* W2     = (const float*)d_in[8];
  const float* b2     = (const float*)d_in[9];
  const float* freq   = (const float*)d_in[10];
  const float* Wout   = (const float*)d_in[11];
  float* out = (float*)d_out;
  short* gk = (short*)d_ws;  // 768*8192*2 B = 12.6 MB filter workspace

  hipLaunchKernelGGL(hyena_filter, dim3(256, 3), dim3(256), 0, stream,
                     z, deltas, W0, b0, W1, b1, W2, b2, freq, Wout, gk);
  hipLaunchKernelGGL(hyena_conv, dim3(768), dim3(1024), 0, stream,
                     x, bias, gk, out);
}